// Round 1
// 1426.769 us; speedup vs baseline: 1.0643x; 1.0643x over previous
//
#include <hip/hip_runtime.h>

// ---- problem constants ----
#define T_TOK 8192
#define HDIM  2048
#define NEXP  8
#define RLORA 16
#define AUX_COEF 0.01f
#define Z_COEF   0.001f
// SCALING = lora_alpha/r = 32/16 = 2
#define SCALE_LORA 2.0f

// ---- grouped GEMM tiling: 256x256 tile, BK=64, 8 waves, 8-phase pipeline ----
#define BK    64
#define KT    32                   // HDIM/BK
#define PAD   256                  // per-expert row padding
#define MAX_TILES 72               // max sum of per-expert ceil(count/256) (<= 64+8)
#define ROWS_CAP (MAX_TILES*PAD)   // 18432
#define NTI   8                    // 2048/256 output col tiles

typedef __attribute__((ext_vector_type(4))) float f4;
typedef __attribute__((ext_vector_type(8))) short s8;
typedef __attribute__((ext_vector_type(4))) unsigned short us4;

__device__ __forceinline__ unsigned short f2b(float f) {
    union { float f; unsigned int u; } c; c.f = f;
    unsigned int u = c.u;
    unsigned int r = (u + 0x7fffu + ((u >> 16) & 1u)) >> 16;  // RNE
    return (unsigned short)r;
}
__device__ __forceinline__ float b2f(unsigned short b) {
    union { unsigned int u; float f; } c; c.u = ((unsigned int)b) << 16;
    return c.f;
}

// async global->LDS, 16B per lane. LDS dst must be wave-uniform base; HW adds lane*16.
__device__ __forceinline__ void async_ld16(const unsigned short* g, const unsigned short* l) {
    __builtin_amdgcn_global_load_lds(
        (const __attribute__((address_space(1))) unsigned int*)(unsigned long long)g,
        (__attribute__((address_space(3))) unsigned int*)(unsigned int)(unsigned long long)l,
        16, 0, 0);
}

// ---------------- init: zero counters + idx_list (ws is poisoned 0xAA each call) ----
__global__ void init_k(int* counts, int* cursors, float* imp, float* zsum, int* idx_list) {
    int i = blockIdx.x * 256 + threadIdx.x;
    if (i < NEXP) { counts[i] = 0; cursors[i] = 0; imp[i] = 0.f; }
    if (i == 0) zsum[0] = 0.f;
    if (i < ROWS_CAP) idx_list[i] = 0;
}

// ---------------- router: logits, top-2, loss partials -----------------------------
__global__ __launch_bounds__(256) void router_k(const float* __restrict__ x,
                                                const float* __restrict__ wg,
                                                int* counts, float* imp, float* zsum,
                                                int* top_e, float* top_g) {
    int wave = threadIdx.x >> 6, lane = threadIdx.x & 63;
    int t = blockIdx.x * 4 + wave;
    float acc[NEXP];
#pragma unroll
    for (int e = 0; e < NEXP; e++) acc[e] = 0.f;
    const float* xr = x + (size_t)t * HDIM;
    for (int k0 = 0; k0 < HDIM; k0 += 256) {
        f4 xv = *(const f4*)(xr + k0 + lane * 4);
#pragma unroll
        for (int e = 0; e < NEXP; e++) {
            f4 wv = *(const f4*)(wg + e * HDIM + k0 + lane * 4);
            acc[e] += xv.x * wv.x + xv.y * wv.y + xv.z * wv.z + xv.w * wv.w;
        }
    }
#pragma unroll
    for (int e = 0; e < NEXP; e++)
        for (int off = 32; off; off >>= 1) acc[e] += __shfl_xor(acc[e], off, 64);
    if (lane == 0) {
        int e0 = 0; float v0 = acc[0];
        for (int e = 1; e < NEXP; e++) if (acc[e] > v0) { v0 = acc[e]; e0 = e; }
        int e1 = -1; float v1 = -1e30f;
        for (int e = 0; e < NEXP; e++) if (e != e0 && acc[e] > v1) { v1 = acc[e]; e1 = e; }
        float ex1 = __expf(v1 - v0);
        float g0 = 1.f / (1.f + ex1), g1 = ex1 / (1.f + ex1);
        top_e[2 * t] = e0; top_e[2 * t + 1] = e1;
        top_g[2 * t] = g0; top_g[2 * t + 1] = g1;
        atomicAdd(&counts[e0], 1); atomicAdd(&counts[e1], 1);
        atomicAdd(&imp[e0], g0);   atomicAdd(&imp[e1], g1);
        float s = 0.f;
        for (int e = 0; e < NEXP; e++) s += __expf(acc[e] - v0);
        float lse = v0 + __logf(s);
        atomicAdd(zsum, lse * lse);
    }
}

// ---------------- scan: padded tile offsets (256-row tiles) + routing loss ----------
__global__ void scan_k(const int* counts, const float* imp, const float* zsum,
                       int* tile_off, int* row_off, int* total_tiles, float* loss_out) {
    if (threadIdx.x == 0 && blockIdx.x == 0) {
        int to = 0;
        float lb = 0.f;
        for (int e = 0; e < NEXP; e++) {
            tile_off[e] = to;
            row_off[e] = to * PAD;
            to += (counts[e] + PAD - 1) / PAD;
            lb += imp[e] * (float)counts[e];
        }
        tile_off[NEXP] = to;
        total_tiles[0] = to;
        float T2 = (float)T_TOK * (float)T_TOK;
        loss_out[0] = AUX_COEF * ((float)NEXP * lb / T2) + Z_COEF * (zsum[0] / (float)T_TOK);
    }
}

// ---------------- assign: compact per-expert slot lists -----------------------------
__global__ void assign_k(const int* top_e, int* cursors, const int* row_off,
                         int* idx_list, int* slotmap) {
    int t = blockIdx.x * 256 + threadIdx.x;
    if (t >= T_TOK) return;
    for (int k = 0; k < 2; k++) {
        int e = top_e[2 * t + k];
        int pos = atomicAdd(&cursors[e], 1);
        int slot = row_off[e] + pos;
        idx_list[slot] = t;
        slotmap[2 * t + k] = slot;
    }
}

// ---------------- cast fp32 x -> bf16 ----------------------------------------------
__global__ __launch_bounds__(256) void cast_k(const float* __restrict__ x,
                                              unsigned short* __restrict__ xb) {
    size_t gid = (size_t)blockIdx.x * 256 + threadIdx.x;
    f4 v = *(const f4*)(x + gid * 4);
    us4 o = { f2b(v.x), f2b(v.y), f2b(v.z), f2b(v.w) };
    *(us4*)(xb + gid * 4) = o;
}

// ---------------- fold: W_eff = W + 2*(B@A), cast to bf16 ---------------------------
__global__ __launch_bounds__(256) void fold_k(const float* __restrict__ w,
                                              const float* __restrict__ A,
                                              const float* __restrict__ B,
                                              unsigned short* __restrict__ out) {
    size_t gid = (size_t)blockIdx.x * 256 + threadIdx.x;
    int h = ((int)(gid & 511)) * 4;          // 512 h-groups
    int o = ((int)((gid >> 9) & 511)) * 4;   // 512 o-groups
    int e = (int)(gid >> 18);
    const float* Ae = A + (size_t)e * RLORA * HDIM;
    f4 av[RLORA];
#pragma unroll
    for (int r = 0; r < RLORA; r++) av[r] = *(const f4*)(Ae + r * HDIM + h);
#pragma unroll
    for (int j = 0; j < 4; j++) {
        const float* Be = B + ((size_t)e * HDIM + o + j) * RLORA;
        f4 acc = {0.f, 0.f, 0.f, 0.f};
#pragma unroll
        for (int r = 0; r < RLORA; r++) acc += Be[r] * av[r];
        size_t woff = ((size_t)e * HDIM + o + j) * HDIM + h;
        f4 wv = *(const f4*)(w + woff);
        f4 res = wv + SCALE_LORA * acc;
        us4 ov = { f2b(res.x), f2b(res.y), f2b(res.z), f2b(res.w) };
        *(us4*)(out + woff) = ov;
    }
}

// ---------------- grouped GEMM: 256x256 tile, 8-phase counted-vmcnt pipeline --------
// LDS: A [buf][256 rows][8 chunk-slots x 16B] at buf*32768 + row*128 + slot*16
//      B same at +65536.  Chunk swizzle: slot = chunk ^ (row&7)  (bank-conflict-free,
//      staged via pre-swizzled per-lane GLOBAL source, linear LDS dest -- rule #21).
// Schedule per iteration (2 K-tiles t0,t0+1; buf = tile&1); per phase:
//   {ds_read frags | issue 1 half-tile global_load_lds | [vmcnt(4) @P3,P7] |
//    barrier | lgkmcnt(0) | setprio(1) 16xMFMA setprio(0) | barrier}
// Staging targets only provably-dead slots:
//   P0,P1: buf1.A(t0+1)  [buf1.A last read prev-iter P7]
//   P2,P3: buf0.B(t0+2)  [buf0.B fully read in P0]
//   P4,P5: buf0.A(t0+2)  [buf0.A last read in P3]
//   P6,P7: buf1.B(t0+3)  [buf1.B fully read in P4]
// vmcnt(4) @P3: 12 outstanding, oldest 8 = buf1 complete.  @P7: oldest 8 = buf0.
// Last iteration wraps staging tiles (refetch, L2-hot) so vmcnt immediates stay uniform.
#define DSR(dst, a) asm volatile("ds_read_b128 %0, %1" : "=v"(dst) : "v"(a))
#define VM_WAIT4 asm volatile("s_waitcnt vmcnt(4)" ::: "memory")
#define VM_NONE ((void)0)
#define STG(PP, DD, BUF, T)                                                                   \
    {                                                                                         \
        async_ld16((PP)[0] + (T) * 64, (const unsigned short*)(smem + (DD)[0] + (BUF) * 32768)); \
        async_ld16((PP)[1] + (T) * 64, (const unsigned short*)(smem + (DD)[1] + (BUF) * 32768)); \
    }
#define PHASE(BUF, P, LOADB, STAGE, VM)                                                       \
    {                                                                                         \
        const unsigned bufo = (BUF) * 32768u;                                                 \
        if (LOADB) {                                                                          \
            _Pragma("unroll") for (int n = 0; n < 4; n++)                                     \
                _Pragma("unroll") for (int s = 0; s < 2; s++)                                 \
                    DSR(bF[n][s], bRd[s] + bufo + n * 2048);                                  \
        }                                                                                     \
        s8 aF[2][2];                                                                          \
        _Pragma("unroll") for (int f = 0; f < 2; f++)                                         \
            _Pragma("unroll") for (int s = 0; s < 2; s++)                                     \
                DSR(aF[f][s], aRd[s] + bufo + (P) * 4096 + f * 2048);                         \
        STAGE;                                                                                \
        VM;                                                                                   \
        __builtin_amdgcn_sched_barrier(0);                                                    \
        __builtin_amdgcn_s_barrier();                                                         \
        asm volatile("s_waitcnt lgkmcnt(0)");                                                 \
        __builtin_amdgcn_sched_barrier(0);                                                    \
        __builtin_amdgcn_s_setprio(1);                                                        \
        _Pragma("unroll") for (int s = 0; s < 2; s++)                                         \
            _Pragma("unroll") for (int f = 0; f < 2; f++)                                     \
                _Pragma("unroll") for (int n = 0; n < 4; n++)                                 \
                    acc[(P) * 2 + f][n] = __builtin_amdgcn_mfma_f32_16x16x32_bf16(            \
                        aF[f][s], bF[n][s], acc[(P) * 2 + f][n], 0, 0, 0);                    \
        __builtin_amdgcn_s_setprio(0);                                                        \
        __builtin_amdgcn_sched_barrier(0);                                                    \
        __builtin_amdgcn_s_barrier();                                                         \
    }

__global__ __launch_bounds__(512, 2) void gemm256_k(const unsigned short* __restrict__ Abase,
                                                    const unsigned short* __restrict__ Wb,
                                                    unsigned short* Cout,
                                                    const unsigned short* gin,
                                                    const int* __restrict__ idx_list,
                                                    const int* __restrict__ tile_off,
                                                    const int* __restrict__ total_tiles,
                                                    int gather, int fuse) {
    // bijective XCD swizzle (grid 576 = 8*72): 8 blocks sharing an A-panel -> same XCD
    int bid = blockIdx.x;
    int wg = (bid & 7) * MAX_TILES + (bid >> 3);
    int tl = wg >> 3, nt = wg & 7;
    if (tl >= total_tiles[0]) return;
    int e = 0;
    while (e < NEXP - 1 && tile_off[e + 1] <= tl) e++;
    int row0 = tl * PAD;
    const unsigned short* We = Wb + ((size_t)e << 22);

    __shared__ char smem[131072];

    int tid = threadIdx.x, lane = tid & 63, w = tid >> 6;
    int wm = w >> 2, wn = w & 3;          // wave grid 2(M) x 4(N); wave out = 128x64
    int srow = lane >> 3;                 // staging row within 8-row wave stripe
    int kseg = ((lane & 7) ^ srow) << 3;  // pre-swizzled global chunk (elements)

    // staging source pointers / LDS dest offsets: [half][j], 2 loads per half-tile
    const unsigned short* aP[2][2];
    const unsigned short* bP[2][2];
    unsigned aD[2][2], bD[2][2];
#pragma unroll
    for (int h = 0; h < 2; h++)
#pragma unroll
        for (int j = 0; j < 2; j++) {
            int r = h * 128 + j * 64 + w * 8 + srow;
            int arow = row0 + r;
            int atok = gather ? idx_list[arow] : arow;
            aP[h][j] = Abase + (size_t)atok * HDIM + kseg;
            bP[h][j] = We + (size_t)(nt * 256 + r) * HDIM + kseg;
            aD[h][j] = (unsigned)((h * 128 + j * 64 + w * 8) * 128);
            bD[h][j] = 65536u + aD[h][j];
        }

    // fragment read base addresses (per kk-slice s), swizzle folded in
    unsigned smem0 = (unsigned)(unsigned long long)(void*)&smem[0];
    int rA = lane & 15, quad = lane >> 4, m3 = rA & 7;
    unsigned aRd[2], bRd[2];
#pragma unroll
    for (int s = 0; s < 2; s++) {
        unsigned sw = (unsigned)(((((s << 2) | quad)) ^ m3) << 4);
        aRd[s] = smem0 + (unsigned)(wm * 16384 + rA * 128) + sw;
        bRd[s] = smem0 + 65536u + (unsigned)(wn * 8192 + rA * 128) + sw;
    }

    f4 acc[8][4];
#pragma unroll
    for (int i = 0; i < 8; i++)
#pragma unroll
        for (int n = 0; n < 4; n++) acc[i][n] = (f4){0.f, 0.f, 0.f, 0.f};

    s8 bF[4][2];

    // prologue: buf0 = tile0 (B,A), buf1.B = tile1.B ; wait tile0, keep tile1.B in flight
    STG(bP[0], bD[0], 0, 0);
    STG(bP[1], bD[1], 0, 0);
    STG(aP[0], aD[0], 0, 0);
    STG(aP[1], aD[1], 0, 0);
    STG(bP[0], bD[0], 1, 1);
    STG(bP[1], bD[1], 1, 1);
    VM_WAIT4;
    __builtin_amdgcn_s_barrier();

#pragma unroll 1
    for (int it = 0; it < KT / 2; ++it) {
        int t0 = 2 * it;
        int t1 = t0 + 1;
        int t2 = (t0 + 2 < KT) ? t0 + 2 : t0;  // wrap keeps vmcnt counts uniform
        int t3 = (t0 + 3 < KT) ? t0 + 3 : t1;
        PHASE(0, 0, 1, STG(aP[0], aD[0], 1, t1), VM_NONE)
        PHASE(0, 1, 0, STG(aP[1], aD[1], 1, t1), VM_NONE)
        PHASE(0, 2, 0, STG(bP[0], bD[0], 0, t2), VM_NONE)
        PHASE(0, 3, 0, STG(bP[1], bD[1], 0, t2), VM_WAIT4)
        PHASE(1, 0, 1, STG(aP[0], aD[0], 0, t2), VM_NONE)
        PHASE(1, 1, 0, STG(aP[1], aD[1], 0, t2), VM_NONE)
        PHASE(1, 2, 0, STG(bP[0], bD[0], 1, t3), VM_NONE)
        PHASE(1, 3, 0, STG(bP[1], bD[1], 1, t3), VM_WAIT4)
    }
    asm volatile("s_waitcnt vmcnt(0) lgkmcnt(0)" ::: "memory");  // drain wrapped stages

    // epilogue: C/D layout col=lane&15, row=(lane>>4)*4+reg
    int cl = lane & 15;
#pragma unroll
    for (int mi = 0; mi < 8; mi++)
#pragma unroll
        for (int n = 0; n < 4; n++)
#pragma unroll
            for (int r = 0; r < 4; r++) {
                int row = row0 + wm * 128 + mi * 16 + quad * 4 + r;
                int col = nt * 256 + wn * 64 + n * 16 + cl;
                size_t off = (size_t)row * HDIM + col;
                float v = acc[mi][n][r];
                if (fuse) {
                    float g = b2f(gin[off]);
                    float sg = g / (1.f + __expf(-g));   // silu(g)
                    v = sg * v;
                }
                Cout[off] = f2b(v);
            }
}

// ---------------- combine: out = hidden + alpha*(g0*y[s0] + g1*y[s1]); -------------
__global__ __launch_bounds__(256) void combine_k(const float* __restrict__ hidden,
                                                 const unsigned short* __restrict__ ybuf,
                                                 const int* __restrict__ slotmap,
                                                 const float* __restrict__ top_g,
                                                 const float* __restrict__ alpha,
                                                 float* __restrict__ out) {
    size_t gid = (size_t)blockIdx.x * 256 + threadIdx.x;
    int t = (int)(gid >> 9);
    int c = ((int)gid & 511) * 4;
    int s0 = slotmap[2 * t], s1 = slotmap[2 * t + 1];
    float g0 = top_g[2 * t], g1 = top_g[2 * t + 1];
    float a = alpha[0];
    f4 hv = *(const f4*)(hidden + ((size_t)t << 11) + c);
    us4 y0 = *(const us4*)(ybuf + ((size_t)s0 << 11) + c);
    us4 y1 = *(const us4*)(ybuf + ((size_t)s1 << 11) + c);
    f4 r;
    r.x = hv.x + a * (g0 * b2f(y0.x) + g1 * b2f(y1.x));
    r.y = hv.y + a * (g0 * b2f(y0.y) + g1 * b2f(y1.y));
    r.z = hv.z + a * (g0 * b2f(y0.z) + g1 * b2f(y1.z));
    r.w = hv.w + a * (g0 * b2f(y0.w) + g1 * b2f(y1.w));
    *(f4*)(out + ((size_t)t << 11) + c) = r;
}

extern "C" void kernel_launch(void* const* d_in, const int* in_sizes, int n_in,
                              void* d_out, int out_size, void* d_ws, size_t ws_size,
                              hipStream_t stream) {
    const float* x      = (const float*)d_in[0];
    const float* w_gate = (const float*)d_in[1];
    const float* gate_w = (const float*)d_in[2];
    const float* gate_A = (const float*)d_in[3];
    const float* gate_B = (const float*)d_in[4];
    const float* up_w   = (const float*)d_in[5];
    const float* up_A   = (const float*)d_in[6];
    const float* up_B   = (const float*)d_in[7];
    const float* down_w = (const float*)d_in[8];
    const float* down_A = (const float*)d_in[9];
    const float* down_B = (const float*)d_in[10];
    const float* alpha  = (const float*)d_in[11];
    float* out = (float*)d_out;

    // ---- workspace carve-up (256B aligned) ----
    // ybuf aliases Xbf (Xbf dead once the up-GEMM ran; ybuf written after) -> ~218 MB,
    // less than the previous version's ~243 MB footprint.
    char* ws = (char*)d_ws;
    size_t off = 0;
    auto carve = [&](size_t bytes) -> void* {
        void* p = ws + off;
        off = (off + bytes + 255) & ~(size_t)255;
        return p;
    };
    int*   counts   = (int*)carve(NEXP * 4);
    int*   cursors  = (int*)carve(NEXP * 4);
    float* imp      = (float*)carve(NEXP * 4);
    float* zsum     = (float*)carve(4);
    int*   tile_off = (int*)carve((NEXP + 1) * 4);
    int*   row_off  = (int*)carve(NEXP * 4);
    int*   total_t  = (int*)carve(4);
    int*   top_e    = (int*)carve(2 * T_TOK * 4);
    float* top_g    = (float*)carve(2 * T_TOK * 4);
    int*   slotmap  = (int*)carve(2 * T_TOK * 4);
    int*   idx_list = (int*)carve(ROWS_CAP * 4);
    unsigned short* gbuf = (unsigned short*)carve((size_t)ROWS_CAP * HDIM * 2);
    unsigned short* Wbuf = (unsigned short*)carve((size_t)NEXP * HDIM * HDIM * 2);
    unsigned short* XYbuf = (unsigned short*)carve((size_t)ROWS_CAP * HDIM * 2);
    unsigned short* Xbf  = XYbuf;   // [T_TOK][HDIM] bf16 (first 33.5 MB of region)
    unsigned short* ybuf = XYbuf;   // [ROWS_CAP][HDIM] bf16 (overwrites Xbf later)

    dim3 blk(256);

    init_k<<<dim3(ROWS_CAP / 256), blk, 0, stream>>>(counts, cursors, imp, zsum, idx_list);
    router_k<<<dim3(T_TOK / 4), blk, 0, stream>>>(x, w_gate, counts, imp, zsum, top_e, top_g);
    scan_k<<<dim3(1), dim3(64), 0, stream>>>(counts, imp, zsum, tile_off, row_off, total_t,
                                             out + (size_t)T_TOK * HDIM);
    assign_k<<<dim3(T_TOK / 256), blk, 0, stream>>>(top_e, cursors, row_off, idx_list, slotmap);
    cast_k<<<dim3((size_t)T_TOK * HDIM / 4 / 256), blk, 0, stream>>>(x, Xbf);

    const int gemm_grid = MAX_TILES * NTI;            // 576
    const int fold_grid = (NEXP * 512 * 512) / 256;   // 8192
    dim3 gblk(512);

    // gate: g = Xe @ Wg_eff.T
    fold_k<<<dim3(fold_grid), blk, 0, stream>>>(gate_w, gate_A, gate_B, Wbuf);
    gemm256_k<<<dim3(gemm_grid), gblk, 0, stream>>>(Xbf, Wbuf, gbuf, gbuf, idx_list, tile_off,
                                                    total_t, 1, 0);
    // up + fused act: a = silu(g) * u  (overwrites gbuf)
    fold_k<<<dim3(fold_grid), blk, 0, stream>>>(up_w, up_A, up_B, Wbuf);
    gemm256_k<<<dim3(gemm_grid), gblk, 0, stream>>>(Xbf, Wbuf, gbuf, gbuf, idx_list, tile_off,
                                                    total_t, 1, 1);
    // down: y = a @ Wd_eff.T   (writes ybuf over the now-dead Xbf region)
    fold_k<<<dim3(fold_grid), blk, 0, stream>>>(down_w, down_A, down_B, Wbuf);
    gemm256_k<<<dim3(gemm_grid), gblk, 0, stream>>>(gbuf, Wbuf, ybuf, ybuf, idx_list, tile_off,
                                                    total_t, 0, 0);

    combine_k<<<dim3((size_t)T_TOK * HDIM / 4 / 256), blk, 0, stream>>>(x, ybuf, slotmap,
                                                                        top_g, alpha, out);
}

// Round 2
// 1077.242 us; speedup vs baseline: 1.4096x; 1.3245x over previous
//
#include <hip/hip_runtime.h>

// ---- problem constants ----
#define T_TOK 8192
#define HDIM  2048
#define NEXP  8
#define RLORA 16
#define AUX_COEF 0.01f
#define Z_COEF   0.001f
// SCALING = lora_alpha/r = 32/16 = 2
#define SCALE_LORA 2.0f

// ---- grouped GEMM tiling: 256x256 tile, BK=64, 8 waves, 8-phase pipeline ----
#define BK    64
#define KT    32                   // HDIM/BK
#define PAD   256                  // per-expert row padding
#define MAX_TILES 72               // max sum of per-expert ceil(count/256)
#define ROWS_CAP (MAX_TILES*PAD)   // 18432
#define NTI   8                    // 2048/256 output col tiles

typedef __attribute__((ext_vector_type(4))) float f4;
typedef __attribute__((ext_vector_type(8))) short s8;
typedef __attribute__((ext_vector_type(4))) unsigned short us4;

__device__ __forceinline__ unsigned short f2b(float f) {
    union { float f; unsigned int u; } c; c.f = f;
    unsigned int u = c.u;
    unsigned int r = (u + 0x7fffu + ((u >> 16) & 1u)) >> 16;  // RNE
    return (unsigned short)r;
}
__device__ __forceinline__ float b2f(unsigned short b) {
    union { unsigned int u; float f; } c; c.u = ((unsigned int)b) << 16;
    return c.f;
}

// async global->LDS, 16B per lane. LDS dst must be wave-uniform base; HW adds lane*16.
__device__ __forceinline__ void async_ld16(const unsigned short* g, const unsigned short* l) {
    __builtin_amdgcn_global_load_lds(
        (const __attribute__((address_space(1))) unsigned int*)(unsigned long long)g,
        (__attribute__((address_space(3))) unsigned int*)(unsigned int)(unsigned long long)l,
        16, 0, 0);
}

// ---------------- init: zero cursors + idx_list (ws is poisoned each call) ---------
__global__ void init_k(int* cursors, int* idx_list) {
    int i = blockIdx.x * 256 + threadIdx.x;
    if (i < NEXP) cursors[i] = 0;
    if (i < ROWS_CAP) idx_list[i] = 0;
}

// ---------------- router: logits, top-2, per-token loss partials, bf16 cast --------
// No global atomics: per-token outputs only (reduce_k aggregates).
// Also converts x -> bf16 Xbf on the fly (kills the separate cast kernel's re-read).
__global__ __launch_bounds__(256) void router_k(const float* __restrict__ x,
                                                const float* __restrict__ wg,
                                                int* top_e, float* top_g, float* lse2,
                                                unsigned short* __restrict__ xb) {
    int wave = threadIdx.x >> 6, lane = threadIdx.x & 63;
    int t = blockIdx.x * 4 + wave;
    float acc[NEXP];
#pragma unroll
    for (int e = 0; e < NEXP; e++) acc[e] = 0.f;
    const float* xr = x + (size_t)t * HDIM;
    unsigned short* xo = xb + (size_t)t * HDIM;
    for (int k0 = 0; k0 < HDIM; k0 += 256) {
        f4 xv = *(const f4*)(xr + k0 + lane * 4);
        us4 ov = { f2b(xv.x), f2b(xv.y), f2b(xv.z), f2b(xv.w) };
        *(us4*)(xo + k0 + lane * 4) = ov;
#pragma unroll
        for (int e = 0; e < NEXP; e++) {
            f4 wv = *(const f4*)(wg + e * HDIM + k0 + lane * 4);
            acc[e] += xv.x * wv.x + xv.y * wv.y + xv.z * wv.z + xv.w * wv.w;
        }
    }
#pragma unroll
    for (int e = 0; e < NEXP; e++)
        for (int off = 32; off; off >>= 1) acc[e] += __shfl_xor(acc[e], off, 64);
    if (lane == 0) {
        int e0 = 0; float v0 = acc[0];
        for (int e = 1; e < NEXP; e++) if (acc[e] > v0) { v0 = acc[e]; e0 = e; }
        int e1 = -1; float v1 = -1e30f;
        for (int e = 0; e < NEXP; e++) if (e != e0 && acc[e] > v1) { v1 = acc[e]; e1 = e; }
        float ex1 = __expf(v1 - v0);
        float g0 = 1.f / (1.f + ex1), g1 = ex1 / (1.f + ex1);
        top_e[2 * t] = e0; top_e[2 * t + 1] = e1;
        top_g[2 * t] = g0; top_g[2 * t + 1] = g1;
        float s = 0.f;
        for (int e = 0; e < NEXP; e++) s += __expf(acc[e] - v0);
        float lse = v0 + __logf(s);
        lse2[t] = lse * lse;
    }
}

// ---------------- reduce: counts/importance/zsum -> tile offsets + loss -------------
__global__ __launch_bounds__(256) void reduce_k(const int* __restrict__ top_e,
                                                const float* __restrict__ top_g,
                                                const float* __restrict__ lse2,
                                                int* tile_off, int* row_off,
                                                int* total_tiles, float* loss_out) {
    int tid = threadIdx.x, lane = tid & 63, wave = tid >> 6;
    float cnt[NEXP], fim[NEXP], z = 0.f;
#pragma unroll
    for (int e = 0; e < NEXP; e++) { cnt[e] = 0.f; fim[e] = 0.f; }
    for (int t = tid; t < T_TOK; t += 256) {
        int e0 = top_e[2 * t], e1 = top_e[2 * t + 1];
        float g0 = top_g[2 * t], g1 = top_g[2 * t + 1];
        z += lse2[t];
#pragma unroll
        for (int e = 0; e < NEXP; e++) {
            cnt[e] += (e0 == e ? 1.f : 0.f) + (e1 == e ? 1.f : 0.f);
            fim[e] += (e0 == e ? g0 : 0.f) + (e1 == e ? g1 : 0.f);
        }
    }
#pragma unroll
    for (int e = 0; e < NEXP; e++)
        for (int off = 32; off; off >>= 1) {
            cnt[e] += __shfl_xor(cnt[e], off, 64);
            fim[e] += __shfl_xor(fim[e], off, 64);
        }
    for (int off = 32; off; off >>= 1) z += __shfl_xor(z, off, 64);
    __shared__ float red[4][2 * NEXP + 1];
    if (lane == 0) {
#pragma unroll
        for (int e = 0; e < NEXP; e++) { red[wave][e] = cnt[e]; red[wave][NEXP + e] = fim[e]; }
        red[wave][2 * NEXP] = z;
    }
    __syncthreads();
    if (tid == 0) {
        float C[NEXP], I[NEXP], Z = 0.f;
#pragma unroll
        for (int e = 0; e < NEXP; e++) { C[e] = 0.f; I[e] = 0.f; }
        for (int w = 0; w < 4; w++) {
#pragma unroll
            for (int e = 0; e < NEXP; e++) { C[e] += red[w][e]; I[e] += red[w][NEXP + e]; }
            Z += red[w][2 * NEXP];
        }
        int to = 0; float lb = 0.f;
        for (int e = 0; e < NEXP; e++) {
            int c = (int)(C[e] + 0.5f);
            tile_off[e] = to;
            row_off[e] = to * PAD;
            to += (c + PAD - 1) / PAD;
            lb += I[e] * (float)c;
        }
        tile_off[NEXP] = to;
        total_tiles[0] = to;
        float T2 = (float)T_TOK * (float)T_TOK;
        loss_out[0] = AUX_COEF * ((float)NEXP * lb / T2) + Z_COEF * (Z / (float)T_TOK);
    }
}

// ---------------- assign: compact per-expert slot lists (wave-aggregated atomics) ---
__global__ void assign_k(const int* __restrict__ top_e, int* cursors,
                         const int* __restrict__ row_off, int* idx_list, int* slotmap) {
    int t = blockIdx.x * 256 + threadIdx.x;
    int lane = threadIdx.x & 63;
    unsigned long long lt = (1ull << lane) - 1ull;
    for (int k = 0; k < 2; k++) {
        int e = top_e[2 * t + k];
        int pos = 0;
#pragma unroll
        for (int ee = 0; ee < NEXP; ee++) {
            unsigned long long m = __ballot(e == ee);
            if (e == ee) {
                int leader = __ffsll((unsigned long long)m) - 1;
                int rank = (int)__popcll(m & lt);
                int base = 0;
                if (lane == leader) base = atomicAdd(&cursors[ee], (int)__popcll(m));
                base = __shfl(base, leader, 64);
                pos = row_off[ee] + base + rank;
            }
        }
        idx_list[pos] = t;
        slotmap[2 * t + k] = pos;
    }
}

// ---------------- fold: W_eff = W + 2*(B@A), cast to bf16 ---------------------------
__global__ __launch_bounds__(256) void fold_k(const float* __restrict__ w,
                                              const float* __restrict__ A,
                                              const float* __restrict__ B,
                                              unsigned short* __restrict__ out) {
    size_t gid = (size_t)blockIdx.x * 256 + threadIdx.x;
    int h = ((int)(gid & 511)) * 4;          // 512 h-groups
    int o = ((int)((gid >> 9) & 511)) * 4;   // 512 o-groups
    int e = (int)(gid >> 18);
    const float* Ae = A + (size_t)e * RLORA * HDIM;
    f4 av[RLORA];
#pragma unroll
    for (int r = 0; r < RLORA; r++) av[r] = *(const f4*)(Ae + r * HDIM + h);
#pragma unroll
    for (int j = 0; j < 4; j++) {
        const float* Be = B + ((size_t)e * HDIM + o + j) * RLORA;
        f4 acc = {0.f, 0.f, 0.f, 0.f};
#pragma unroll
        for (int r = 0; r < RLORA; r++) acc += Be[r] * av[r];
        size_t woff = ((size_t)e * HDIM + o + j) * HDIM + h;
        f4 wv = *(const f4*)(w + woff);
        f4 res = wv + SCALE_LORA * acc;
        us4 ov = { f2b(res.x), f2b(res.y), f2b(res.z), f2b(res.w) };
        *(us4*)(out + woff) = ov;
    }
}

// ---------------- grouped GEMM: 256x256 tile, 8-phase counted-vmcnt pipeline --------
// Template-exact quadrant phases (m201): per K-tile 4 phases over (m-half, n-half):
//   P0 (m0,n0): read A-half0 (8 b128) + B n0-1 (4)  [12 reads -> lgkmcnt(8) throttle]
//   P1 (m0,n1): read B n2-3 (4)
//   P2 (m1,n1): read A-half1 (8)
//   P3 (m1,n0): no reads
// Staging (2 x global_load_lds per phase) into provably-dead slots; vmcnt(4) at the
// last phase of each K-tile only (never 0 in the loop). LDS chunk-XOR swizzle via
// pre-swizzled global source (rule #21), conflict-free b128 fragment reads.
#define DSR(dst, a) asm volatile("ds_read_b128 %0, %1" : "=v"(dst) : "v"(a))
#define VM_WAIT4 asm volatile("s_waitcnt vmcnt(4)" ::: "memory")
#define LGKM0 asm volatile("s_waitcnt lgkmcnt(0)")
#define LGKM8 asm volatile("s_waitcnt lgkmcnt(8)")
#define BARX __builtin_amdgcn_s_barrier()
#define SBX  __builtin_amdgcn_sched_barrier(0)
#define STG(PP, DD, BUF, T)                                                                      \
    {                                                                                            \
        async_ld16((PP)[0] + (T) * 64, (const unsigned short*)(smem + (DD)[0] + (BUF) * 32768)); \
        async_ld16((PP)[1] + (T) * 64, (const unsigned short*)(smem + (DD)[1] + (BUF) * 32768)); \
    }
#define RDA(HALF, BO)                                                                            \
    _Pragma("unroll") for (int m_ = 0; m_ < 4; m_++)                                             \
        _Pragma("unroll") for (int s_ = 0; s_ < 2; s_++)                                         \
            DSR(aF[m_][s_], aRd[s_] + (BO) + ((HALF) * 4 + m_) * 2048);
#define RDB(PAIR, BO)                                                                            \
    _Pragma("unroll") for (int n_ = 0; n_ < 2; n_++)                                             \
        _Pragma("unroll") for (int s_ = 0; s_ < 2; s_++)                                         \
            DSR(bF[(PAIR) * 2 + n_][s_], bRd[s_] + (BO) + ((PAIR) * 2 + n_) * 2048);
#define MFMAQ(MH, NH)                                                                            \
    __builtin_amdgcn_s_setprio(1);                                                               \
    _Pragma("unroll") for (int s_ = 0; s_ < 2; s_++)                                             \
        _Pragma("unroll") for (int m_ = 0; m_ < 4; m_++)                                         \
            _Pragma("unroll") for (int n_ = 0; n_ < 2; n_++)                                     \
                acc[(MH) * 4 + m_][(NH) * 2 + n_] = __builtin_amdgcn_mfma_f32_16x16x32_bf16(     \
                    aF[m_][s_], bF[(NH) * 2 + n_][s_], acc[(MH) * 4 + m_][(NH) * 2 + n_], 0, 0, 0); \
    __builtin_amdgcn_s_setprio(0);
#define KPASS(BUF, TA, TB)                                                                       \
    {                                                                                            \
        const unsigned bo = (BUF) * 32768u;                                                      \
        /* P0 */                                                                                 \
        RDA(0, bo) RDB(0, bo)                                                                    \
        STG(aP[0], aD[0], (BUF) ^ 1, TA);                                                        \
        LGKM8; SBX; BARX; LGKM0; SBX;                                                            \
        MFMAQ(0, 0) SBX; BARX;                                                                   \
        /* P1 */                                                                                 \
        RDB(1, bo)                                                                               \
        STG(aP[1], aD[1], (BUF) ^ 1, TA);                                                        \
        SBX; BARX; LGKM0; SBX;                                                                   \
        MFMAQ(0, 1) SBX; BARX;                                                                   \
        /* P2 */                                                                                 \
        RDA(1, bo)                                                                               \
        STG(bP[0], bD[0], (BUF), TB);                                                            \
        SBX; BARX; LGKM0; SBX;                                                                   \
        MFMAQ(1, 1) SBX; BARX;                                                                   \
        /* P3 */                                                                                 \
        STG(bP[1], bD[1], (BUF), TB);                                                            \
        VM_WAIT4; SBX; BARX; SBX;                                                                \
        MFMAQ(1, 0) SBX; BARX;                                                                   \
    }

__global__ __launch_bounds__(512, 2) void gemm256_k(const unsigned short* Abase,
                                                    const unsigned short* Wb,
                                                    unsigned short* Cout,
                                                    const unsigned short* gin,
                                                    const int* __restrict__ idx_list,
                                                    const int* __restrict__ tile_off,
                                                    const int* __restrict__ total_tiles,
                                                    int gather, int fuse,
                                                    const unsigned short* Wb2,
                                                    unsigned short* Cout2) {
    if (blockIdx.y) { Wb = Wb2; Cout = Cout2; }
    // bijective XCD swizzle (576 = 8*72): blocks sharing an A-panel -> same XCD's L2
    int bid = blockIdx.x;
    int wg = (bid & 7) * MAX_TILES + (bid >> 3);
    int tl = wg >> 3, nt = wg & 7;
    if (tl >= total_tiles[0]) return;
    int e = 0;
    while (e < NEXP - 1 && tile_off[e + 1] <= tl) e++;
    int row0 = tl * PAD;
    const unsigned short* We = Wb + ((size_t)e << 22);

    __shared__ char smem[131072];

    int tid = threadIdx.x, lane = tid & 63, w = tid >> 6;
    int wm = w >> 2, wn = w & 3;          // wave grid 2(M) x 4(N); wave out = 128x64
    int srow = lane >> 3;                 // staging row within 8-row wave stripe
    int kseg = ((lane & 7) ^ srow) << 3;  // pre-swizzled global chunk (elements)

    const unsigned short* aP[2][2];
    const unsigned short* bP[2][2];
    unsigned aD[2][2], bD[2][2];
#pragma unroll
    for (int h = 0; h < 2; h++)
#pragma unroll
        for (int j = 0; j < 2; j++) {
            int r = h * 128 + j * 64 + w * 8 + srow;
            int arow = row0 + r;
            int atok = gather ? idx_list[arow] : arow;
            aP[h][j] = Abase + (size_t)atok * HDIM + kseg;
            bP[h][j] = We + (size_t)(nt * 256 + r) * HDIM + kseg;
            aD[h][j] = (unsigned)((h * 128 + j * 64 + w * 8) * 128);
            bD[h][j] = 65536u + aD[h][j];
        }

    // fragment read base addresses (per kk-slice s), swizzle folded in
    unsigned smem0 = (unsigned)(unsigned long long)(void*)&smem[0];
    int rA = lane & 15, quad = lane >> 4, m3 = rA & 7;
    unsigned aRd[2], bRd[2];
#pragma unroll
    for (int s = 0; s < 2; s++) {
        unsigned sw = (unsigned)(((((s << 2) | quad)) ^ m3) << 4);
        aRd[s] = smem0 + (unsigned)(wm * 16384 + rA * 128) + sw;
        bRd[s] = smem0 + 65536u + (unsigned)(wn * 8192 + rA * 128) + sw;
    }

    f4 acc[8][4];
#pragma unroll
    for (int i = 0; i < 8; i++)
#pragma unroll
        for (int n = 0; n < 4; n++) acc[i][n] = (f4){0.f, 0.f, 0.f, 0.f};

    s8 aF[4][2];
    s8 bF[4][2];

    // prologue: buf0 = tile0 (B,A), buf1.B = tile1.B ; wait tile0, keep tile1.B in flight
    STG(bP[0], bD[0], 0, 0);
    STG(bP[1], bD[1], 0, 0);
    STG(aP[0], aD[0], 0, 0);
    STG(aP[1], aD[1], 0, 0);
    STG(bP[0], bD[0], 1, 1);
    STG(bP[1], bD[1], 1, 1);
    VM_WAIT4;
    BARX;

#pragma unroll 1
    for (int it = 0; it < KT / 2; ++it) {
        int t0 = 2 * it;
        int t1 = t0 + 1;
        int t2 = (t0 + 2 < KT) ? t0 + 2 : t0;  // wrap keeps vmcnt counts uniform
        int t3 = (t0 + 3 < KT) ? t0 + 3 : t1;
        KPASS(0, t1, t2)
        KPASS(1, t2, t3)
    }
    asm volatile("s_waitcnt vmcnt(0) lgkmcnt(0)" ::: "memory");  // drain wrapped stages

    // epilogue: C/D layout col=lane&15, row=(lane>>4)*4+reg
    int cl = lane & 15;
#pragma unroll
    for (int mi = 0; mi < 8; mi++)
#pragma unroll
        for (int n = 0; n < 4; n++)
#pragma unroll
            for (int r = 0; r < 4; r++) {
                int row = row0 + wm * 128 + mi * 16 + quad * 4 + r;
                int col = nt * 256 + wn * 64 + n * 16 + cl;
                size_t off = (size_t)row * HDIM + col;
                float v = acc[mi][n][r];
                if (fuse) {
                    float g = b2f(gin[off]);
                    float sg = g / (1.f + __expf(-g));   // silu(g)
                    v = sg * v;
                }
                Cout[off] = f2b(v);
            }
}

// ---------------- silu-mul: a = silu(g) * u, in place over g (merged path) ----------
__global__ __launch_bounds__(256) void silu_k(unsigned short* __restrict__ g,
                                              const unsigned short* __restrict__ u,
                                              const int* __restrict__ total_tiles) {
    size_t gid = (size_t)blockIdx.x * 256 + threadIdx.x;
    int row = (int)(gid >> 8);                 // 8 elems/thread, 256 groups per row
    if (row >= total_tiles[0] * PAD) return;
    s8 gv = *(const s8*)(g + gid * 8);
    s8 uv = *(const s8*)(u + gid * 8);
    s8 ov;
#pragma unroll
    for (int j = 0; j < 8; j++) {
        float gf = b2f((unsigned short)gv[j]);
        float uf = b2f((unsigned short)uv[j]);
        float sg = gf / (1.f + __expf(-gf));
        ov[j] = (short)f2b(sg * uf);
    }
    *(s8*)(g + gid * 8) = ov;
}

// ---------------- combine: out = hidden + alpha*(g0*y[s0] + g1*y[s1]) ---------------
__global__ __launch_bounds__(256) void combine_k(const float* __restrict__ hidden,
                                                 const unsigned short* __restrict__ ybuf,
                                                 const int* __restrict__ slotmap,
                                                 const float* __restrict__ top_g,
                                                 const float* __restrict__ alpha,
                                                 float* __restrict__ out) {
    size_t gid = (size_t)blockIdx.x * 256 + threadIdx.x;
    int t = (int)(gid >> 9);
    int c = ((int)gid & 511) * 4;
    int s0 = slotmap[2 * t], s1 = slotmap[2 * t + 1];
    float g0 = top_g[2 * t], g1 = top_g[2 * t + 1];
    float a = alpha[0];
    f4 hv = *(const f4*)(hidden + ((size_t)t << 11) + c);
    us4 y0 = *(const us4*)(ybuf + ((size_t)s0 << 11) + c);
    us4 y1 = *(const us4*)(ybuf + ((size_t)s1 << 11) + c);
    f4 r;
    r.x = hv.x + a * (g0 * b2f(y0.x) + g1 * b2f(y1.x));
    r.y = hv.y + a * (g0 * b2f(y0.y) + g1 * b2f(y1.y));
    r.z = hv.z + a * (g0 * b2f(y0.z) + g1 * b2f(y1.z));
    r.w = hv.w + a * (g0 * b2f(y0.w) + g1 * b2f(y1.w));
    *(f4*)(out + ((size_t)t << 11) + c) = r;
}

extern "C" void kernel_launch(void* const* d_in, const int* in_sizes, int n_in,
                              void* d_out, int out_size, void* d_ws, size_t ws_size,
                              hipStream_t stream) {
    const float* x      = (const float*)d_in[0];
    const float* w_gate = (const float*)d_in[1];
    const float* gate_w = (const float*)d_in[2];
    const float* gate_A = (const float*)d_in[3];
    const float* gate_B = (const float*)d_in[4];
    const float* up_w   = (const float*)d_in[5];
    const float* up_A   = (const float*)d_in[6];
    const float* up_B   = (const float*)d_in[7];
    const float* down_w = (const float*)d_in[8];
    const float* down_A = (const float*)d_in[9];
    const float* down_B = (const float*)d_in[10];
    const float* alpha  = (const float*)d_in[11];
    float* out = (float*)d_out;

    // Xbf (bf16 x) lives in the OUTPUT buffer: dead until combine_k rewrites all of
    // out at the very end; loss slot (out + T*H) is beyond the 33.5 MB Xbf region.
    unsigned short* Xbf = (unsigned short*)out;

    // ---- workspace carve-up (256B aligned) ----
    char* ws = (char*)d_ws;
    size_t off = 0;
    auto carve = [&](size_t bytes) -> void* {
        void* p = ws + off;
        off = (off + bytes + 255) & ~(size_t)255;
        return p;
    };
    int*   cursors  = (int*)carve(NEXP * 4);
    int*   tile_off = (int*)carve((NEXP + 1) * 4);
    int*   row_off  = (int*)carve(NEXP * 4);
    int*   total_t  = (int*)carve(4);
    int*   top_e    = (int*)carve(2 * T_TOK * 4);
    float* top_g    = (float*)carve(2 * T_TOK * 4);
    int*   slotmap  = (int*)carve(2 * T_TOK * 4);
    int*   idx_list = (int*)carve(ROWS_CAP * 4);
    float* lse2     = (float*)carve(T_TOK * 4);
    unsigned short* gbuf  = (unsigned short*)carve((size_t)ROWS_CAP * HDIM * 2);
    unsigned short* XYbuf = (unsigned short*)carve((size_t)ROWS_CAP * HDIM * 2);
    unsigned short* Wbuf  = (unsigned short*)carve((size_t)NEXP * HDIM * HDIM * 2);
    size_t base_need = off;
    unsigned short* Wbuf2 = (unsigned short*)carve((size_t)NEXP * HDIM * HDIM * 2);
    int merged = (ws_size >= off) ? 1 : 0;
    (void)base_need;

    unsigned short* ubuf = XYbuf;   // merged path: raw up output (dead before ybuf)
    unsigned short* ybuf = XYbuf;   // down output

    dim3 blk(256);

    init_k<<<dim3(ROWS_CAP / 256), blk, 0, stream>>>(cursors, idx_list);
    router_k<<<dim3(T_TOK / 4), blk, 0, stream>>>(x, w_gate, top_e, top_g, lse2, Xbf);
    reduce_k<<<dim3(1), blk, 0, stream>>>(top_e, top_g, lse2, tile_off, row_off, total_t,
                                          out + (size_t)T_TOK * HDIM);
    assign_k<<<dim3(T_TOK / 256), blk, 0, stream>>>(top_e, cursors, row_off, idx_list, slotmap);

    const int gemm_grid = MAX_TILES * NTI;            // 576
    const int fold_grid = (NEXP * 512 * 512) / 256;   // 8192
    dim3 gblk(512);

    if (merged) {
        // gate+up in ONE launch (independent, share A-tiles); silu in separate pass
        fold_k<<<dim3(fold_grid), blk, 0, stream>>>(gate_w, gate_A, gate_B, Wbuf);
        fold_k<<<dim3(fold_grid), blk, 0, stream>>>(up_w, up_A, up_B, Wbuf2);
        gemm256_k<<<dim3(gemm_grid, 2), gblk, 0, stream>>>(Xbf, Wbuf, gbuf, gbuf, idx_list,
                                                           tile_off, total_t, 1, 0, Wbuf2, ubuf);
        silu_k<<<dim3(ROWS_CAP), blk, 0, stream>>>(gbuf, ubuf, total_t);
        fold_k<<<dim3(fold_grid), blk, 0, stream>>>(down_w, down_A, down_B, Wbuf);
        gemm256_k<<<dim3(gemm_grid), gblk, 0, stream>>>(gbuf, Wbuf, ybuf, ybuf, idx_list,
                                                        tile_off, total_t, 0, 0, Wbuf, ybuf);
    } else {
        // sequential fallback: silu fused into up-GEMM epilogue (reads gbuf)
        fold_k<<<dim3(fold_grid), blk, 0, stream>>>(gate_w, gate_A, gate_B, Wbuf);
        gemm256_k<<<dim3(gemm_grid), gblk, 0, stream>>>(Xbf, Wbuf, gbuf, gbuf, idx_list,
                                                        tile_off, total_t, 1, 0, Wbuf, gbuf);
        fold_k<<<dim3(fold_grid), blk, 0, stream>>>(up_w, up_A, up_B, Wbuf);
        gemm256_k<<<dim3(gemm_grid), gblk, 0, stream>>>(Xbf, Wbuf, gbuf, gbuf, idx_list,
                                                        tile_off, total_t, 1, 1, Wbuf, gbuf);
        fold_k<<<dim3(fold_grid), blk, 0, stream>>>(down_w, down_A, down_B, Wbuf);
        gemm256_k<<<dim3(gemm_grid), gblk, 0, stream>>>(gbuf, Wbuf, ybuf, ybuf, idx_list,
                                                        tile_off, total_t, 0, 0, Wbuf, ybuf);
    }

    combine_k<<<dim3((size_t)T_TOK * HDIM / 4 / 256), blk, 0, stream>>>(x, ybuf, slotmap,
                                                                        top_g, alpha, out);
}